// Round 2
// baseline (474.494 us; speedup 1.0000x reference)
//
#include <hip/hip_runtime.h>
#include <stdint.h>

// ---------------- Kernel A: per-row stats ----------------
// support = proj(mobius_add(coef*dot, hyp_bias)); coef = atanh(min(n,1-1e-7))/n
// base = (1-w1)*(1-n) + b
__global__ __launch_bounds__(256) void rowstats(
    const float* __restrict__ x, const float* __restrict__ w,
    const float* __restrict__ bias, const float* __restrict__ w1p,
    const float* __restrict__ bp,
    float* __restrict__ support, float* __restrict__ coef,
    double* __restrict__ base, int N)
{
    int wv = threadIdx.x >> 6, lane = threadIdx.x & 63;
    int row = blockIdx.x * 4 + wv;
    if (row >= N) return;
    const float4* xr = (const float4*)(x + (size_t)row * 512);
    const float4* wr = (const float4*)(w);
    float dot = 0.f, ss = 0.f;
#pragma unroll
    for (int it = 0; it < 2; it++) {
        float4 xv = xr[lane + it * 64];
        float4 wv4 = wr[lane + it * 64];
        dot += xv.x * wv4.x + xv.y * wv4.y + xv.z * wv4.z + xv.w * wv4.w;
        ss  += xv.x * xv.x + xv.y * xv.y + xv.z * xv.z + xv.w * xv.w;
    }
    for (int off = 32; off; off >>= 1) {
        dot += __shfl_xor(dot, off);
        ss  += __shfl_xor(ss, off);
    }
    if (lane == 0) {
        double n = sqrt((double)ss); if (n < 1e-15) n = 1e-15;
        double t = n; const double lim = 1.0 - 1e-7; if (t > lim) t = lim;
        double cf = atanh(t) / n;
        double s = cf * (double)dot;
        // hyp_bias = proj(expmap0(bias))
        double b0 = (double)bias[0];
        double nb = fabs(b0); if (nb < 1e-15) nb = 1e-15;
        double hb = tanh(nb) * b0 / nb;
        const double maxn = 0.996;  // (1-4e-3)/sqrt(1)
        double nh = fabs(hb); if (nh < 1e-15) nh = 1e-15;
        if (nh > maxn) hb = hb / nh * maxn;
        // mobius_add(s, hb), c=1
        double x2 = s * s, y2 = hb * hb, xy = s * hb;
        double num = (1.0 + 2.0 * xy + y2) * s + (1.0 - x2) * hb;
        double den = 1.0 + 2.0 * xy + x2 * y2;
        if (den < 1e-15) den = 1e-15;
        double r = num / den;
        double nr = fabs(r); if (nr < 1e-15) nr = 1e-15;
        if (nr > maxn) r = r / nr * maxn;
        support[row] = (float)r;
        coef[row] = (float)cf;
        double w1 = (double)w1p[0];
        double bb = (double)bp[0];
        base[row] = (1.0 - w1) * (1.0 - n) + bb;
    }
}

// ---------------- Kernel B: SpMV, deterministic fixed-point ----------------
__global__ __launch_bounds__(256) void spmv(
    const int* __restrict__ rows, const int* __restrict__ cols,
    const float* __restrict__ adj, const float* __restrict__ support,
    unsigned long long* __restrict__ agg, int E)
{
    int e = blockIdx.x * 256 + threadIdx.x;
    if (e >= E) return;
    float a = adj[e];
    float s = support[cols[e]];
    double p = (double)a * (double)s;
    long long f = llrint(p * 1099511627776.0); // 2^40
    atomicAdd(&agg[rows[e]], (unsigned long long)f);
}

// ---------------- Kernel C: attn + keys + coarse histogram ----------------
__global__ __launch_bounds__(256) void attn_kernel(
    const unsigned long long* __restrict__ agg, const double* __restrict__ base,
    const float* __restrict__ w1p,
    float* __restrict__ attn, uint32_t* __restrict__ keys,
    uint32_t* __restrict__ hist1, float* __restrict__ attn_out, int N)
{
    int i = blockIdx.x * 256 + threadIdx.x;
    if (i >= N) return;
    double a = (double)(long long)agg[i] * (1.0 / 1099511627776.0);
    // score = proj(expmap0(agg))
    double na = fabs(a); if (na < 1e-15) na = 1e-15;
    double sc_ = tanh(na) * a / na;
    const double maxn = 0.996;
    double ns = fabs(sc_); if (ns < 1e-15) ns = 1e-15;
    if (ns > maxn) sc_ = sc_ / ns * maxn;
    double w1 = (double)w1p[0];
    double at = w1 * tanh(sc_) + base[i];
    float af = (float)at;
    attn[i] = af;
    attn_out[i] = af;
    union { float f; uint32_t u; } cv; cv.f = af;
    uint32_t key = cv.u ^ ((cv.u >> 31) ? 0xFFFFFFFFu : 0x80000000u);
    keys[i] = key;
    atomicAdd(&hist1[key >> 16], 1u);
}

// ---------------- find bucket containing k-th largest ----------------
// mode 0: high 16 bits, writes M[0]=bucket, M[1]=count strictly above bucket
// mode 1: low 16 bits, writes M[2]=tau key
__global__ __launch_bounds__(1024) void select_bucket(
    const uint32_t* __restrict__ hist, uint32_t* M, int mode, uint32_t k)
{
    __shared__ uint32_t lds[1024];
    int t = threadIdx.x;
    uint32_t ktarget = (mode == 0) ? k : (k - M[1]);
    uint32_t csum = 0;
    for (int j = 0; j < 64; j++) csum += hist[t * 64 + j];
    lds[t] = csum;
    __syncthreads();
    for (int off = 1; off < 1024; off <<= 1) {
        uint32_t v = (t + off < 1024) ? lds[t + off] : 0u;
        __syncthreads();
        lds[t] += v;
        __syncthreads();
    }
    uint32_t run = (t + 1 < 1024) ? lds[t + 1] : 0u; // suffix sum excl my chunk
    for (int j = 63; j >= 0; j--) {
        uint32_t c = hist[t * 64 + j];
        uint32_t nr = run + c;
        if (nr >= ktarget && run < ktarget) {
            if (mode == 0) { M[0] = (uint32_t)(t * 64 + j); M[1] = run; }
            else           { M[2] = (M[0] << 16) | (uint32_t)(t * 64 + j); }
        }
        run = nr;
    }
}

__global__ __launch_bounds__(256) void hist_low(
    const uint32_t* __restrict__ keys, const uint32_t* __restrict__ M,
    uint32_t* __restrict__ hist2, int N)
{
    int i = blockIdx.x * 256 + threadIdx.x;
    if (i >= N) return;
    uint32_t key = keys[i];
    if ((key >> 16) == M[0]) atomicAdd(&hist2[key & 0xFFFFu], 1u);
}

// ---------------- selection prefix machinery ----------------
__global__ __launch_bounds__(256) void blocksum(
    const uint32_t* __restrict__ keys, const uint32_t* __restrict__ M,
    uint32_t* __restrict__ bs, uint32_t* __restrict__ bt, int N)
{
    __shared__ uint32_t ls[4], lt[4];
    uint32_t tau = M[2];
    int base_i = blockIdx.x * 1024 + threadIdx.x * 4;
    uint32_t cs = 0, ct = 0;
    for (int j = 0; j < 4; j++) {
        int i = base_i + j;
        if (i < N) {
            uint32_t kk = keys[i];
            cs += (kk > tau);
            ct += (kk == tau);
        }
    }
    for (int off = 32; off; off >>= 1) {
        cs += __shfl_xor(cs, off);
        ct += __shfl_xor(ct, off);
    }
    int lane = threadIdx.x & 63, wv = threadIdx.x >> 6;
    if (lane == 0) { ls[wv] = cs; lt[wv] = ct; }
    __syncthreads();
    if (threadIdx.x == 0) {
        uint32_t a = 0, b = 0;
        for (int wq = 0; wq < 4; wq++) { a += ls[wq]; b += lt[wq]; }
        bs[blockIdx.x] = a; bt[blockIdx.x] = b;
    }
}

__global__ void scanblocks(
    uint32_t* M, const uint32_t* __restrict__ bs, const uint32_t* __restrict__ bt,
    uint32_t* __restrict__ ss, uint32_t* __restrict__ st, int nb, uint32_t k)
{
    if (threadIdx.x == 0 && blockIdx.x == 0) {
        uint32_t a = 0, b = 0;
        for (int i = 0; i < nb; i++) {
            ss[i] = a; st[i] = b;
            a += bs[i]; b += bt[i];
        }
        M[3] = k - a; // ties needed
    }
}

__global__ __launch_bounds__(256) void select_write(
    const uint32_t* __restrict__ keys, const uint32_t* __restrict__ M,
    const uint32_t* __restrict__ ss, const uint32_t* __restrict__ st,
    uint32_t* __restrict__ sel, int N)
{
    uint32_t tau = M[2], need = M[3];
    int t = threadIdx.x, lane = t & 63, wv = t >> 6;
    int base_i = blockIdx.x * 1024 + t * 4;
    uint32_t fs[4], ft[4];
    uint32_t cs = 0, ct = 0;
    for (int j = 0; j < 4; j++) {
        int i = base_i + j;
        uint32_t kk = (i < N) ? keys[i] : 0u;
        fs[j] = (i < N) && (kk > tau);
        ft[j] = (i < N) && (kk == tau);
        cs += fs[j]; ct += ft[j];
    }
    uint32_t is_ = cs, it_ = ct;
    for (int off = 1; off < 64; off <<= 1) {
        uint32_t vs = __shfl_up(is_, off);
        uint32_t vt = __shfl_up(it_, off);
        if (lane >= off) { is_ += vs; it_ += vt; }
    }
    uint32_t wes = is_ - cs, wet = it_ - ct;
    __shared__ uint32_t lws[4], lwt[4];
    if (lane == 63) { lws[wv] = is_; lwt[wv] = it_; }
    __syncthreads();
    uint32_t wos = 0, wot = 0;
    for (int wq = 0; wq < wv; wq++) { wos += lws[wq]; wot += lwt[wq]; }
    uint32_t gs = ss[blockIdx.x] + wos + wes;
    uint32_t gt = st[blockIdx.x] + wot + wet;
    for (int j = 0; j < 4; j++) {
        int i = base_i + j;
        if (fs[j]) {
            uint32_t pos = gs + (gt < need ? gt : need);
            sel[pos] = (uint32_t)i;
        } else if (ft[j]) {
            if (gt < need) sel[gs + gt] = (uint32_t)i;
        }
        gs += fs[j]; gt += ft[j];
    }
}

// ---------------- Kernel E: write hidden rows ----------------
__global__ __launch_bounds__(256) void write_hidden(
    const float* __restrict__ x, const uint32_t* __restrict__ sel,
    const float* __restrict__ attn, const float* __restrict__ coef,
    float* __restrict__ out, int K)
{
    int wv = threadIdx.x >> 6, lane = threadIdx.x & 63;
    int p = blockIdx.x * 4 + wv;
    if (p >= K) return;
    uint32_t i = sel[p];
    float s = attn[i] * coef[i];
    const float4* xr = (const float4*)(x + (size_t)i * 512);
    float4* orow = (float4*)(out + (size_t)p * 512);
#pragma unroll
    for (int it = 0; it < 2; it++) {
        float4 v = xr[lane + it * 64];
        float4 o;
        o.x = v.x * s; o.y = v.y * s; o.z = v.z * s; o.w = v.w * s;
        orow[lane + it * 64] = o;
    }
}

extern "C" void kernel_launch(void* const* d_in, const int* in_sizes, int n_in,
                              void* d_out, int out_size, void* d_ws, size_t ws_size,
                              hipStream_t stream)
{
    const float* x    = (const float*)d_in[0];
    const float* adj  = (const float*)d_in[1];
    const float* w    = (const float*)d_in[2];
    const float* bias = (const float*)d_in[3];
    const float* w1p  = (const float*)d_in[4];
    const float* bp   = (const float*)d_in[5];
    const int* erow = (const int*)d_in[6];
    const int* ecol = (const int*)d_in[7];

    int D = in_sizes[2];          // 512
    int N = in_sizes[0] / D;      // 100000
    int E = in_sizes[1];          // 3200000
    int K = N / 2;                // keep_ratio 0.5

    char* ws = (char*)d_ws;
    unsigned long long* agg = (unsigned long long*)(ws);              // N*8 @ 0
    float*   support = (float*)(ws + (1 << 20));                      // N*4 @ 1MB
    float*   coef    = (float*)(ws + (1 << 20) + (512 << 10));        // N*4 @ 1.5MB
    double*  base    = (double*)(ws + (2 << 20));                     // N*8 @ 2MB
    float*   attn    = (float*)(ws + (3 << 20));                      // N*4 @ 3MB
    uint32_t* keys   = (uint32_t*)(ws + (3 << 20) + (512 << 10));     // N*4 @ 3.5MB
    uint32_t* hist1  = (uint32_t*)(ws + (4 << 20));                   // 64K*4 @ 4MB
    uint32_t* hist2  = (uint32_t*)(ws + (4 << 20) + (512 << 10));     // 64K*4 @ 4.5MB
    uint32_t* M      = (uint32_t*)(ws + (5 << 20));                   // misc @ 5MB
    uint32_t* bs  = M + 8;
    uint32_t* bt  = M + 8 + 128;
    uint32_t* ss_ = M + 8 + 256;
    uint32_t* st_ = M + 8 + 384;
    uint32_t* sel = (uint32_t*)(ws + (5 << 20) + (512 << 10));        // K*4 @ 5.5MB

    float* hidden_out = (float*)d_out;
    float* attn_out   = (float*)d_out + (size_t)K * D;

    hipMemsetAsync(agg, 0, (size_t)N * 8, stream);
    hipMemsetAsync(ws + (4 << 20), 0, (1 << 20) + 4096, stream); // hist1,hist2,M,bs,bt

    rowstats<<<(N + 3) / 4, 256, 0, stream>>>(x, w, bias, w1p, bp, support, coef, base, N);
    spmv<<<(E + 255) / 256, 256, 0, stream>>>(erow, ecol, adj, support, agg, E);
    attn_kernel<<<(N + 255) / 256, 256, 0, stream>>>(agg, base, w1p, attn, keys, hist1, attn_out, N);
    select_bucket<<<1, 1024, 0, stream>>>(hist1, M, 0, (uint32_t)K);
    hist_low<<<(N + 255) / 256, 256, 0, stream>>>(keys, M, hist2, N);
    select_bucket<<<1, 1024, 0, stream>>>(hist2, M, 1, (uint32_t)K);
    int nb = (N + 1023) / 1024;
    blocksum<<<nb, 256, 0, stream>>>(keys, M, bs, bt, N);
    scanblocks<<<1, 64, 0, stream>>>(M, bs, bt, ss_, st_, nb, (uint32_t)K);
    select_write<<<nb, 256, 0, stream>>>(keys, M, ss_, st_, sel, N);
    write_hidden<<<(K + 3) / 4, 256, 0, stream>>>(x, sel, attn, coef, hidden_out, K);
}